// Round 4
// baseline (355.328 us; speedup 1.0000x reference)
//
#include <hip/hip_runtime.h>

#define NF 64

// ---------------- CSR build ----------------

__global__ __launch_bounds__(256) void k_init(int* degc, int n) {
    int i = blockIdx.x * 256 + threadIdx.x;
    if (i < n) degc[i] = 1;                      // self-loop counts
}

__global__ __launch_bounds__(256) void k_count(const int* __restrict__ dst, int* degc, int e) {
    int i = blockIdx.x * 256 + threadIdx.x;
    if (i < e) atomicAdd(&degc[dst[i]], 1);
}

// chunk sums for scan + dinv (fused: both read degc)
__global__ __launch_bounds__(256) void k_scan_a(const int* __restrict__ degc, int* partial,
                                                float* __restrict__ dinv, int n) {
    __shared__ int sh[256];
    int t = threadIdx.x, i = blockIdx.x * 256 + t;
    int v = (i < n) ? degc[i] : 0;
    if (i < n) dinv[i] = rsqrtf((float)v);       // deg includes self -> >=1
    sh[t] = v;
    __syncthreads();
    for (int off = 128; off > 0; off >>= 1) {
        if (t < off) sh[t] += sh[t + off];
        __syncthreads();
    }
    if (t == 0) partial[blockIdx.x] = sh[0];
}

// exclusive scan of chunk sums (single block, nb <= 512)
__global__ __launch_bounds__(512) void k_scan_b(int* partial, int nb) {
    __shared__ int sh[512];
    int t = threadIdx.x;
    int v = (t < nb) ? partial[t] : 0;
    sh[t] = v;
    __syncthreads();
    for (int off = 1; off < 512; off <<= 1) {
        int u = (t >= off) ? sh[t - off] : 0;
        __syncthreads();
        sh[t] += u;
        __syncthreads();
    }
    if (t < nb) partial[t] = sh[t] - v;   // exclusive
}

// per-chunk scan + base; plant self-edge; init cursor past it
__global__ __launch_bounds__(256) void k_scan_c(const int* __restrict__ degc,
                                                const int* __restrict__ partial,
                                                int* offsets, int* cursor, int* csr, int n) {
    __shared__ int sh[256];
    int t = threadIdx.x, i = blockIdx.x * 256 + t;
    int v = (i < n) ? degc[i] : 0;
    sh[t] = v;
    __syncthreads();
    for (int off = 1; off < 256; off <<= 1) {
        int u = (t >= off) ? sh[t - off] : 0;
        __syncthreads();
        sh[t] += u;
        __syncthreads();
    }
    if (i < n) {
        int o = partial[blockIdx.x] + sh[t] - v;
        offsets[i] = o;
        csr[o] = i;              // self-edge first
        cursor[i] = o + 1;
        if (i == n - 1) offsets[n] = o + v;
    }
}

__global__ __launch_bounds__(256) void k_fill(const int* __restrict__ src,
                                              const int* __restrict__ dst,
                                              int* cursor, int* csr, int e) {
    int i = blockIdx.x * 256 + threadIdx.x;
    if (i >= e) return;
    int slot = atomicAdd(&cursor[dst[i]], 1);
    csr[slot] = src[i];
}

// ---------------- fused gather-aggregate + GEMM epilogue ----------------
// 4 nodes per wave (16 lanes x float4 each); vsh exchange is wave-local -> no barriers.

__global__ __launch_bounds__(256) void k_agg_gemm(const float* __restrict__ x,
                                                  const float* __restrict__ W,
                                                  const float* __restrict__ bias,
                                                  const float* __restrict__ dinv,
                                                  const int* __restrict__ offsets,
                                                  const int* __restrict__ csr,
                                                  float* __restrict__ out, int n) {
    __shared__ float wt[NF * NF];      // wt[k*64+j] = W[j][k]
    __shared__ float vsh[16][NF];
    int tid = threadIdx.x;
    // stage W^T via float4 reads of W
    for (int idx = tid; idx < 1024; idx += 256) {
        int j = idx >> 4, k0 = (idx & 15) << 2;
        float4 w4 = *reinterpret_cast<const float4*>(W + j * NF + k0);
        wt[(k0 + 0) * NF + j] = w4.x;
        wt[(k0 + 1) * NF + j] = w4.y;
        wt[(k0 + 2) * NF + j] = w4.z;
        wt[(k0 + 3) * NF + j] = w4.w;
    }
    int wave = tid >> 6, lane = tid & 63;
    int slot = lane >> 4, ln = lane & 15;
    float bj = bias[lane];
    __syncthreads();                   // wt staged (only barrier in kernel)

    int ngroups = (n + 15) >> 4;
    for (int g = blockIdx.x; g < ngroups; g += gridDim.x) {
        int d = g * 16 + wave * 4 + slot;
        float4 acc = {0.f, 0.f, 0.f, 0.f};
        if (d < n) {
            float dd = dinv[d];
            int i = offsets[d], end = offsets[d + 1];
            float4 a0 = {0.f, 0.f, 0.f, 0.f}, a1 = {0.f, 0.f, 0.f, 0.f};
            for (; i + 1 < end; i += 2) {
                int s0 = csr[i], s1 = csr[i + 1];
                float w0 = dinv[s0], w1 = dinv[s1];
                const float4 v0 = *reinterpret_cast<const float4*>(x + (long)s0 * NF + ln * 4);
                const float4 v1 = *reinterpret_cast<const float4*>(x + (long)s1 * NF + ln * 4);
                a0.x = fmaf(v0.x, w0, a0.x); a0.y = fmaf(v0.y, w0, a0.y);
                a0.z = fmaf(v0.z, w0, a0.z); a0.w = fmaf(v0.w, w0, a0.w);
                a1.x = fmaf(v1.x, w1, a1.x); a1.y = fmaf(v1.y, w1, a1.y);
                a1.z = fmaf(v1.z, w1, a1.z); a1.w = fmaf(v1.w, w1, a1.w);
            }
            if (i < end) {
                int s = csr[i];
                float w = dinv[s];
                const float4 v = *reinterpret_cast<const float4*>(x + (long)s * NF + ln * 4);
                a0.x = fmaf(v.x, w, a0.x); a0.y = fmaf(v.y, w, a0.y);
                a0.z = fmaf(v.z, w, a0.z); a0.w = fmaf(v.w, w, a0.w);
            }
            acc.x = dd * (a0.x + a1.x);
            acc.y = dd * (a0.y + a1.y);
            acc.z = dd * (a0.z + a1.z);
            acc.w = dd * (a0.w + a1.w);
        }
        // wave-local transpose via LDS (produce+consume by same wave; compiler orders via lgkmcnt)
        *reinterpret_cast<float4*>(&vsh[wave * 4 + slot][ln * 4]) = acc;

        float r0 = bj, r1 = bj, r2 = bj, r3 = bj;
#pragma unroll
        for (int k0 = 0; k0 < NF; k0 += 4) {
            float4 b0 = *reinterpret_cast<const float4*>(&vsh[wave * 4 + 0][k0]);
            float4 b1 = *reinterpret_cast<const float4*>(&vsh[wave * 4 + 1][k0]);
            float4 b2 = *reinterpret_cast<const float4*>(&vsh[wave * 4 + 2][k0]);
            float4 b3 = *reinterpret_cast<const float4*>(&vsh[wave * 4 + 3][k0]);
            float w0 = wt[(k0 + 0) * NF + lane];
            float w1 = wt[(k0 + 1) * NF + lane];
            float w2 = wt[(k0 + 2) * NF + lane];
            float w3 = wt[(k0 + 3) * NF + lane];
            r0 = fmaf(b0.x, w0, r0); r0 = fmaf(b0.y, w1, r0); r0 = fmaf(b0.z, w2, r0); r0 = fmaf(b0.w, w3, r0);
            r1 = fmaf(b1.x, w0, r1); r1 = fmaf(b1.y, w1, r1); r1 = fmaf(b1.z, w2, r1); r1 = fmaf(b1.w, w3, r1);
            r2 = fmaf(b2.x, w0, r2); r2 = fmaf(b2.y, w1, r2); r2 = fmaf(b2.z, w2, r2); r2 = fmaf(b2.w, w3, r2);
            r3 = fmaf(b3.x, w0, r3); r3 = fmaf(b3.y, w1, r3); r3 = fmaf(b3.z, w2, r3); r3 = fmaf(b3.w, w3, r3);
        }
        int base = g * 16 + wave * 4;
        if (base + 0 < n) out[(long)(base + 0) * NF + lane] = r0;
        if (base + 1 < n) out[(long)(base + 1) * NF + lane] = r1;
        if (base + 2 < n) out[(long)(base + 2) * NF + lane] = r2;
        if (base + 3 < n) out[(long)(base + 3) * NF + lane] = r3;
    }
}

// ---------------- launch ----------------

extern "C" void kernel_launch(void* const* d_in, const int* in_sizes, int n_in,
                              void* d_out, int out_size, void* d_ws, size_t ws_size,
                              hipStream_t stream) {
    const float* x    = (const float*)d_in[0];
    const int*   ei   = (const int*)d_in[1];   // harness pushes integers as int32
    const float* W    = (const float*)d_in[2];
    const float* bias = (const float*)d_in[3];
    float*       out  = (float*)d_out;

    const int n = in_sizes[0] / NF;       // 100000
    const int e = in_sizes[1] / 2;        // 1250000
    const int* src = ei;
    const int* dst = ei + e;

    // workspace layout (~7.0MB)
    int*   degc    = (int*)d_ws;           // n
    float* dinv    = (float*)(degc + n);   // n
    int*   offsets = (int*)(dinv + n);     // n+1
    int*   cursor  = offsets + n + 1;      // n
    int*   partial = cursor + n;           // up to 512
    int*   csr     = partial + 512;        // e + n

    const int nb = (n + 255) / 256;        // 391 (<= 512)
    dim3 blk(256);

    k_init  <<<nb, blk, 0, stream>>>(degc, n);
    k_count <<<(e + 255) / 256, blk, 0, stream>>>(dst, degc, e);
    k_scan_a<<<nb, blk, 0, stream>>>(degc, partial, dinv, n);
    k_scan_b<<<1, 512, 0, stream>>>(partial, nb);
    k_scan_c<<<nb, blk, 0, stream>>>(degc, partial, offsets, cursor, csr, n);
    k_fill  <<<(e + 255) / 256, blk, 0, stream>>>(src, dst, cursor, csr, e);
    k_agg_gemm<<<2048, blk, 0, stream>>>(x, W, bias, dinv, offsets, csr, out, n);
}

// Round 5
// 281.106 us; speedup vs baseline: 1.2640x; 1.2640x over previous
//
#include <hip/hip_runtime.h>

#define NF 64

// ---------------- CSR build ----------------

__global__ __launch_bounds__(256) void k_count(const int* __restrict__ dst, int* degc, int e) {
    int i = blockIdx.x * 256 + threadIdx.x;
    if (i < e) atomicAdd(&degc[dst[i]], 1);
}

// one kernel: block scan of (deg+1) + atomic base alloc; writes offsets/ends/cursor,
// plants self-edge, computes dinv. CSR slot ORDER across blocks is arbitrary (gather
// doesn't care), which is what lets us skip the 3-phase exact scan.
__global__ __launch_bounds__(256) void k_offsets(const int* __restrict__ degc,
                                                 int* counter,
                                                 int* __restrict__ offsets,
                                                 int* __restrict__ ends,
                                                 int* __restrict__ cursor,
                                                 int* __restrict__ csr,
                                                 float* __restrict__ dinv, int n) {
    __shared__ int sh[256];
    __shared__ int shbase;
    int t = threadIdx.x, i = blockIdx.x * 256 + t;
    int v = (i < n) ? degc[i] + 1 : 0;          // +1 self-loop
    sh[t] = v;
    __syncthreads();
    for (int off = 1; off < 256; off <<= 1) {   // inclusive scan
        int u = (t >= off) ? sh[t - off] : 0;
        __syncthreads();
        sh[t] += u;
        __syncthreads();
    }
    if (t == 0) shbase = atomicAdd(counter, sh[255]);
    __syncthreads();
    if (i < n) {
        int o = shbase + sh[t] - v;             // exclusive within block + base
        offsets[i] = o;
        ends[i] = o + v;
        csr[o] = i;                             // self-edge first
        cursor[i] = o + 1;
        dinv[i] = rsqrtf((float)v);
    }
}

__global__ __launch_bounds__(256) void k_fill(const int* __restrict__ src,
                                              const int* __restrict__ dst,
                                              int* cursor, int* csr, int e) {
    int i = blockIdx.x * 256 + threadIdx.x;
    if (i >= e) return;
    int slot = atomicAdd(&cursor[dst[i]], 1);
    csr[slot] = src[i];
}

// ---------------- fused gather-aggregate + GEMM epilogue ----------------
// 1 node per wave, lane = feature (scalar acc -> low VGPR). No in-loop barriers:
// vsh[wv] is produced and consumed by the same wave (same-wave LDS ordering).

__global__ __launch_bounds__(256) void k_agg_gemm(const float* __restrict__ x,
                                                  const float* __restrict__ W,
                                                  const float* __restrict__ bias,
                                                  const float* __restrict__ dinv,
                                                  const int* __restrict__ offsets,
                                                  const int* __restrict__ ends,
                                                  const int* __restrict__ csr,
                                                  float* __restrict__ out, int n) {
    __shared__ float wt[NF * NF];      // wt[k*64+j] = W[j][k]
    __shared__ float vsh[4][NF];
    int tid = threadIdx.x;
    for (int idx = tid; idx < NF * NF; idx += 256) {
        int k = idx >> 6, j = idx & 63;
        wt[idx] = W[j * NF + k];
    }
    int wv = tid >> 6, lane = tid & 63;
    float bj = bias[lane];
    __syncthreads();                   // wt staged (only barrier)

    int ngroups = (n + 3) >> 2;
    for (int g = blockIdx.x; g < ngroups; g += gridDim.x) {
        int d = g * 4 + wv;
        if (d >= n) continue;
        int i = offsets[d], end = ends[d];
        float a0 = 0.f, a1 = 0.f, a2 = 0.f, a3 = 0.f;
        for (; i + 3 < end; i += 4) {          // 4 independent gather chains
            int s0 = csr[i], s1 = csr[i + 1], s2 = csr[i + 2], s3 = csr[i + 3];
            float w0 = dinv[s0], w1 = dinv[s1], w2 = dinv[s2], w3 = dinv[s3];
            a0 = fmaf(x[(long)s0 * NF + lane], w0, a0);
            a1 = fmaf(x[(long)s1 * NF + lane], w1, a1);
            a2 = fmaf(x[(long)s2 * NF + lane], w2, a2);
            a3 = fmaf(x[(long)s3 * NF + lane], w3, a3);
        }
        for (; i < end; ++i) {
            int s = csr[i];
            a0 = fmaf(x[(long)s * NF + lane], dinv[s], a0);
        }
        float v = dinv[d] * ((a0 + a1) + (a2 + a3));   // self-edge already in csr

        vsh[wv][lane] = v;                     // wave-local exchange, no barrier
        float r = bj;
#pragma unroll
        for (int k0 = 0; k0 < NF; k0 += 4) {
            float4 bv = *reinterpret_cast<const float4*>(&vsh[wv][k0]);  // broadcast
            r = fmaf(bv.x, wt[(k0 + 0) * NF + lane], r);
            r = fmaf(bv.y, wt[(k0 + 1) * NF + lane], r);
            r = fmaf(bv.z, wt[(k0 + 2) * NF + lane], r);
            r = fmaf(bv.w, wt[(k0 + 3) * NF + lane], r);
        }
        out[(long)d * NF + lane] = r;
    }
}

// ---------------- launch ----------------

extern "C" void kernel_launch(void* const* d_in, const int* in_sizes, int n_in,
                              void* d_out, int out_size, void* d_ws, size_t ws_size,
                              hipStream_t stream) {
    const float* x    = (const float*)d_in[0];
    const int*   ei   = (const int*)d_in[1];   // harness pushes integers as int32
    const float* W    = (const float*)d_in[2];
    const float* bias = (const float*)d_in[3];
    float*       out  = (float*)d_out;

    const int n = in_sizes[0] / NF;       // 100000
    const int e = in_sizes[1] / 2;        // 1250000
    const int* src = ei;
    const int* dst = ei + e;

    // workspace layout (~10MB)
    int*   degc    = (int*)d_ws;           // n   (zeroed each call)
    int*   counter = degc + n;             // 1   (zeroed each call)
    float* dinv    = (float*)(counter + 1);// n
    int*   offsets = (int*)(dinv + n);     // n
    int*   ends    = offsets + n;          // n
    int*   cursor  = ends + n;             // n
    int*   csr     = cursor + n;           // e + n

    const int nb = (n + 255) / 256;
    dim3 blk(256);

    hipMemsetAsync(degc, 0, (size_t)(n + 1) * sizeof(int), stream);  // degc + counter
    k_count  <<<(e + 255) / 256, blk, 0, stream>>>(dst, degc, e);
    k_offsets<<<nb, blk, 0, stream>>>(degc, counter, offsets, ends, cursor, csr, dinv, n);
    k_fill   <<<(e + 255) / 256, blk, 0, stream>>>(src, dst, cursor, csr, e);
    k_agg_gemm<<<2048, blk, 0, stream>>>(x, W, bias, dinv, offsets, ends, csr, out, n);
}

// Round 6
// 239.035 us; speedup vs baseline: 1.4865x; 1.1760x over previous
//
#include <hip/hip_runtime.h>

#define NF 64
#define OCAP 65536

// ---------------- single-pass ELL build (ELL lives inside d_out!) ----------------
// out row d (64 floats) doubles as node d's ELL slot array (<=64 int32 srcs).
// slot order is arbitrary (gather) -> one edge pass, no scan, no csr buffer.

__global__ __launch_bounds__(256) void k_ell(const int* __restrict__ src,
                                             const int* __restrict__ dst,
                                             int* degc, int* ocnt, int* oflow,
                                             int* outi, int e) {
    int i = blockIdx.x * 256 + threadIdx.x;
    if (i >= e) return;
    int s = src[i], d = dst[i];
    int slot = atomicAdd(&degc[d], 1);
    if (slot < NF) {
        outi[(long)d * NF + slot] = s;
    } else {                                   // ~never for this dataset; correctness fallback
        int o = atomicAdd(ocnt, 1);
        if (o < OCAP) { oflow[2 * o] = s; oflow[2 * o + 1] = d; }
    }
}

__global__ __launch_bounds__(256) void k_dinv(const int* __restrict__ degc,
                                              float* __restrict__ dinv, int n) {
    int i = blockIdx.x * 256 + threadIdx.x;
    if (i < n) dinv[i] = rsqrtf((float)(degc[i] + 1));   // +1 self-loop
}

// ---------------- fused gather-aggregate + GEMM epilogue ----------------
// 2 nodes per wave, lane = feature. ELL row read as one coalesced 256B int load;
// edge srcs redistributed via __shfl. 8 independent x-row gather chains per wave.
// No in-loop barriers (vsh is wave-local). Row d: read ints -> write floats, same wave.

__global__ __launch_bounds__(256) void k_agg_gemm(const float* __restrict__ x,
                                                  const float* __restrict__ W,
                                                  const float* __restrict__ bias,
                                                  const float* __restrict__ dinv,
                                                  const int* __restrict__ degc,
                                                  float* __restrict__ out, int n) {
    __shared__ float wt[NF * NF];      // wt[k*64+j] = W[j][k]
    __shared__ float vsh[4][2][NF];
    int tid = threadIdx.x;
    for (int idx = tid; idx < NF * NF; idx += 256) {
        int k = idx >> 6, j = idx & 63;
        wt[idx] = W[j * NF + k];
    }
    int wv = tid >> 6, lane = tid & 63;
    float bj = bias[lane];
    __syncthreads();                   // wt staged (only barrier)

    const int* outi = (const int*)out;   // ELL aliased in out
    int ngroups = (n + 7) >> 3;          // 8 nodes per block-iteration
    for (int g = blockIdx.x; g < ngroups; g += gridDim.x) {
        int d0 = g * 8 + wv * 2, d1 = d0 + 1;
        bool ok0 = d0 < n, ok1 = d1 < n;
        int sd0 = ok0 ? d0 : 0, sd1 = ok1 ? d1 : 0;
        int ev0 = outi[(long)sd0 * NF + lane];            // ELL rows (256B coalesced)
        int ev1 = outi[(long)sd1 * NF + lane];
        int m0 = ok0 ? min(degc[sd0], NF) : 0;
        int m1 = ok1 ? min(degc[sd1], NF) : 0;
        float dd0 = ok0 ? dinv[sd0] : 0.f;
        float dd1 = ok1 ? dinv[sd1] : 0.f;

        float a00 = 0.f, a01 = 0.f, a02 = 0.f, a03 = 0.f;
        float a10 = 0.f, a11 = 0.f, a12 = 0.f, a13 = 0.f;
        // self-loop term (s = d, weight dinv[d]; dd=0 masks invalid)
        a00 = fmaf(x[(long)sd0 * NF + lane], dd0, a00);
        a10 = fmaf(x[(long)sd1 * NF + lane], dd1, a10);

        int mm = max(m0, m1);
        for (int j = 0; j < mm; j += 4) {
            int s00 = __shfl(ev0, j + 0), s01 = __shfl(ev0, j + 1);
            int s02 = __shfl(ev0, j + 2), s03 = __shfl(ev0, j + 3);
            int s10 = __shfl(ev1, j + 0), s11 = __shfl(ev1, j + 1);
            int s12 = __shfl(ev1, j + 2), s13 = __shfl(ev1, j + 3);
            bool b00 = j + 0 < m0, b01 = j + 1 < m0, b02 = j + 2 < m0, b03 = j + 3 < m0;
            bool b10 = j + 0 < m1, b11 = j + 1 < m1, b12 = j + 2 < m1, b13 = j + 3 < m1;
            s00 = b00 ? s00 : 0; s01 = b01 ? s01 : 0; s02 = b02 ? s02 : 0; s03 = b03 ? s03 : 0;
            s10 = b10 ? s10 : 0; s11 = b11 ? s11 : 0; s12 = b12 ? s12 : 0; s13 = b13 ? s13 : 0;
            float w00 = b00 ? dinv[s00] : 0.f, w01 = b01 ? dinv[s01] : 0.f;
            float w02 = b02 ? dinv[s02] : 0.f, w03 = b03 ? dinv[s03] : 0.f;
            float w10 = b10 ? dinv[s10] : 0.f, w11 = b11 ? dinv[s11] : 0.f;
            float w12 = b12 ? dinv[s12] : 0.f, w13 = b13 ? dinv[s13] : 0.f;
            a00 = fmaf(x[(long)s00 * NF + lane], w00, a00);
            a01 = fmaf(x[(long)s01 * NF + lane], w01, a01);
            a02 = fmaf(x[(long)s02 * NF + lane], w02, a02);
            a03 = fmaf(x[(long)s03 * NF + lane], w03, a03);
            a10 = fmaf(x[(long)s10 * NF + lane], w10, a10);
            a11 = fmaf(x[(long)s11 * NF + lane], w11, a11);
            a12 = fmaf(x[(long)s12 * NF + lane], w12, a12);
            a13 = fmaf(x[(long)s13 * NF + lane], w13, a13);
        }
        float v0 = dd0 * ((a00 + a01) + (a02 + a03));
        float v1 = dd1 * ((a10 + a11) + (a12 + a13));

        vsh[wv][0][lane] = v0;                 // wave-local exchange, no barrier
        vsh[wv][1][lane] = v1;
        float r0 = bj, r1 = bj;
#pragma unroll
        for (int k0 = 0; k0 < NF; k0 += 4) {
            float4 b0 = *reinterpret_cast<const float4*>(&vsh[wv][0][k0]);
            float4 b1 = *reinterpret_cast<const float4*>(&vsh[wv][1][k0]);
            float q0 = wt[(k0 + 0) * NF + lane];
            float q1 = wt[(k0 + 1) * NF + lane];
            float q2 = wt[(k0 + 2) * NF + lane];
            float q3 = wt[(k0 + 3) * NF + lane];
            r0 = fmaf(b0.x, q0, r0); r0 = fmaf(b0.y, q1, r0);
            r0 = fmaf(b0.z, q2, r0); r0 = fmaf(b0.w, q3, r0);
            r1 = fmaf(b1.x, q0, r1); r1 = fmaf(b1.y, q1, r1);
            r1 = fmaf(b1.z, q2, r1); r1 = fmaf(b1.w, q3, r1);
        }
        if (ok0) out[(long)d0 * NF + lane] = r0;
        if (ok1) out[(long)d1 * NF + lane] = r1;
    }
}

// ---------------- overflow fixup (post-GEMM, by linearity) ----------------
__global__ __launch_bounds__(64) void k_oflow(const float* __restrict__ x,
                                              const float* __restrict__ W,
                                              const float* __restrict__ dinv,
                                              const int* __restrict__ ocnt,
                                              const int* __restrict__ oflow,
                                              float* out) {
    int c = *ocnt; if (c > OCAP) c = OCAP;
    int lane = threadIdx.x;
    for (int o = blockIdx.x; o < c; o += gridDim.x) {
        int s = oflow[2 * o], d = oflow[2 * o + 1];
        float norm = dinv[s] * dinv[d];
        float r = 0.f;
        for (int k = 0; k < NF; ++k)
            r = fmaf(x[(long)s * NF + k], W[lane * NF + k], r);
        atomicAdd(&out[(long)d * NF + lane], norm * r);
    }
}

// ---------------- launch ----------------

extern "C" void kernel_launch(void* const* d_in, const int* in_sizes, int n_in,
                              void* d_out, int out_size, void* d_ws, size_t ws_size,
                              hipStream_t stream) {
    const float* x    = (const float*)d_in[0];
    const int*   ei   = (const int*)d_in[1];   // harness pushes integers as int32
    const float* W    = (const float*)d_in[2];
    const float* bias = (const float*)d_in[3];
    float*       out  = (float*)d_out;

    const int n = in_sizes[0] / NF;       // 100000
    const int e = in_sizes[1] / 2;        // 1250000
    const int* src = ei;
    const int* dst = ei + e;

    // workspace (~1.3MB): degc n | ocnt 1 | dinv n | oflow 2*OCAP
    int*   degc  = (int*)d_ws;
    int*   ocnt  = degc + n;
    float* dinv  = (float*)(ocnt + 1);
    int*   oflow = (int*)(dinv + n);

    dim3 blk(256);
    hipMemsetAsync(degc, 0, (size_t)(n + 1) * sizeof(int), stream);  // degc + ocnt
    k_ell <<<(e + 255) / 256, blk, 0, stream>>>(src, dst, degc, ocnt, oflow, (int*)out, e);
    k_dinv<<<(n + 255) / 256, blk, 0, stream>>>(degc, dinv, n);
    k_agg_gemm<<<2048, blk, 0, stream>>>(x, W, bias, dinv, degc, out, n);
    k_oflow<<<64, 64, 0, stream>>>(x, W, dinv, ocnt, oflow, out);
}

// Round 7
// 199.250 us; speedup vs baseline: 1.7833x; 1.1997x over previous
//
#include <hip/hip_runtime.h>

#define NF 64
#define ELLS 48
#define OCAP 65536

// ---------------- single-pass slot-major ELL build ----------------
// ell[slot*n + d] = src. Slot-major => writes cluster in a rolling ~1-2MB
// frontier (slot regions fill in order) -> L2-resident, dense lines.
// Fused degree count via the atomic slot allocation.

__global__ __launch_bounds__(256) void k_ell(const int* __restrict__ src,
                                             const int* __restrict__ dst,
                                             int* degc, int* ocnt, int* oflow,
                                             int* __restrict__ ell, int e, int n) {
    int i = blockIdx.x * 256 + threadIdx.x;
    if (i >= e) return;
    int s = src[i], d = dst[i];
    int slot = atomicAdd(&degc[d], 1);
    if (slot < ELLS) {
        ell[(long)slot * n + d] = s;
    } else {                                   // P(deg>48)~1e-13; correctness fallback
        int o = atomicAdd(ocnt, 1);
        if (o < OCAP) { oflow[2 * o] = s; oflow[2 * o + 1] = d; }
    }
}

__global__ __launch_bounds__(256) void k_dinv(const int* __restrict__ degc,
                                              float* __restrict__ dinv, int n) {
    int i = blockIdx.x * 256 + threadIdx.x;
    if (i < n) dinv[i] = rsqrtf((float)(degc[i] + 1));   // +1 self-loop
}

// ---------------- fused gather-aggregate + GEMM epilogue ----------------
// 1 node/wave, lane = feature. ELL row read slot-major per-lane (lane = slot,
// 4 consecutive d share each 64B line -> L1 reuse across the block's 4 waves).
// Next-iteration ELL/degc prefetched before the gather loop. 8 independent
// gather chains. No in-loop barriers (vsh is wave-local).

__global__ __launch_bounds__(256) void k_agg_gemm(const float* __restrict__ x,
                                                  const float* __restrict__ W,
                                                  const float* __restrict__ bias,
                                                  const float* __restrict__ dinv,
                                                  const int* __restrict__ degc,
                                                  const int* __restrict__ ell,
                                                  float* __restrict__ out, int n) {
    __shared__ float wt[NF * NF];      // wt[k*64+j] = W[j][k]
    __shared__ float vsh[4][NF];
    int tid = threadIdx.x;
    for (int idx = tid; idx < NF * NF; idx += 256) {
        int k = idx >> 6, j = idx & 63;
        wt[idx] = W[j * NF + k];
    }
    int wv = tid >> 6, lane = tid & 63;
    float bj = bias[lane];
    __syncthreads();                   // wt staged (only barrier)

    int ngroups = (n + 3) >> 2, gs = gridDim.x;
    int g = blockIdx.x;
    int d = g * 4 + wv;
    int ev = 0, mc = 0;
    if (d < n) {
        if (lane < ELLS) ev = ell[(long)lane * n + d];
        mc = degc[d];
    }
    while (g < ngroups) {
        int gn = g + gs, dn = gn * 4 + wv;
        int evn = 0, mcn = 0;
        if (gn < ngroups && dn < n) {          // prefetch next iteration
            if (lane < ELLS) evn = ell[(long)lane * n + dn];
            mcn = degc[dn];
        }
        if (d < n) {
            float dd = rsqrtf((float)(mc + 1));
            int m = min(mc, ELLS);
            float a0 = x[(long)d * NF + lane] * dd;    // self term
            float a1 = 0.f, a2 = 0.f, a3 = 0.f, a4 = 0.f, a5 = 0.f, a6 = 0.f, a7 = 0.f;
            for (int j = 0; j < m; j += 8) {           // 8 independent gather chains
                int s0 = __shfl(ev, j + 0), s1 = __shfl(ev, j + 1);
                int s2 = __shfl(ev, j + 2), s3 = __shfl(ev, j + 3);
                int s4 = __shfl(ev, j + 4), s5 = __shfl(ev, j + 5);
                int s6 = __shfl(ev, j + 6), s7 = __shfl(ev, j + 7);
                bool b0 = j + 0 < m, b1 = j + 1 < m, b2 = j + 2 < m, b3 = j + 3 < m;
                bool b4 = j + 4 < m, b5 = j + 5 < m, b6 = j + 6 < m, b7 = j + 7 < m;
                s0 = b0 ? s0 : 0; s1 = b1 ? s1 : 0; s2 = b2 ? s2 : 0; s3 = b3 ? s3 : 0;
                s4 = b4 ? s4 : 0; s5 = b5 ? s5 : 0; s6 = b6 ? s6 : 0; s7 = b7 ? s7 : 0;
                float w0 = b0 ? dinv[s0] : 0.f, w1 = b1 ? dinv[s1] : 0.f;
                float w2 = b2 ? dinv[s2] : 0.f, w3 = b3 ? dinv[s3] : 0.f;
                float w4 = b4 ? dinv[s4] : 0.f, w5 = b5 ? dinv[s5] : 0.f;
                float w6 = b6 ? dinv[s6] : 0.f, w7 = b7 ? dinv[s7] : 0.f;
                a0 = fmaf(x[(long)s0 * NF + lane], w0, a0);
                a1 = fmaf(x[(long)s1 * NF + lane], w1, a1);
                a2 = fmaf(x[(long)s2 * NF + lane], w2, a2);
                a3 = fmaf(x[(long)s3 * NF + lane], w3, a3);
                a4 = fmaf(x[(long)s4 * NF + lane], w4, a4);
                a5 = fmaf(x[(long)s5 * NF + lane], w5, a5);
                a6 = fmaf(x[(long)s6 * NF + lane], w6, a6);
                a7 = fmaf(x[(long)s7 * NF + lane], w7, a7);
            }
            float v = dd * (((a0 + a1) + (a2 + a3)) + ((a4 + a5) + (a6 + a7)));

            vsh[wv][lane] = v;                 // wave-local exchange, no barrier
            float r = bj;
#pragma unroll
            for (int k0 = 0; k0 < NF; k0 += 4) {
                float4 bv = *reinterpret_cast<const float4*>(&vsh[wv][k0]);  // broadcast
                r = fmaf(bv.x, wt[(k0 + 0) * NF + lane], r);
                r = fmaf(bv.y, wt[(k0 + 1) * NF + lane], r);
                r = fmaf(bv.z, wt[(k0 + 2) * NF + lane], r);
                r = fmaf(bv.w, wt[(k0 + 3) * NF + lane], r);
            }
            out[(long)d * NF + lane] = r;
        }
        g = gn; d = dn; ev = evn; mc = mcn;
    }
}

// ---------------- overflow fixup (post-GEMM, by linearity) ----------------
__global__ __launch_bounds__(64) void k_oflow(const float* __restrict__ x,
                                              const float* __restrict__ W,
                                              const float* __restrict__ dinv,
                                              const int* __restrict__ ocnt,
                                              const int* __restrict__ oflow,
                                              float* out) {
    int c = *ocnt; if (c > OCAP) c = OCAP;
    int lane = threadIdx.x;
    for (int o = blockIdx.x; o < c; o += gridDim.x) {
        int s = oflow[2 * o], d = oflow[2 * o + 1];
        float norm = dinv[s] * dinv[d];
        float r = 0.f;
        for (int k = 0; k < NF; ++k)
            r = fmaf(x[(long)s * NF + k], W[lane * NF + k], r);
        atomicAdd(&out[(long)d * NF + lane], norm * r);
    }
}

// ---------------- launch ----------------

extern "C" void kernel_launch(void* const* d_in, const int* in_sizes, int n_in,
                              void* d_out, int out_size, void* d_ws, size_t ws_size,
                              hipStream_t stream) {
    const float* x    = (const float*)d_in[0];
    const int*   ei   = (const int*)d_in[1];   // harness pushes integers as int32
    const float* W    = (const float*)d_in[2];
    const float* bias = (const float*)d_in[3];
    float*       out  = (float*)d_out;

    const int n = in_sizes[0] / NF;       // 100000
    const int e = in_sizes[1] / 2;        // 1250000
    const int* src = ei;
    const int* dst = ei + e;

    // ws layout (~20.5MB; 26.4MB proven available in R2):
    // degc n | ocnt 1 | dinv n | oflow 2*OCAP | ell ELLS*n
    int*   degc  = (int*)d_ws;
    int*   ocnt  = degc + n;
    float* dinv  = (float*)(ocnt + 1);
    int*   oflow = (int*)(dinv + n);
    int*   ell   = oflow + 2 * OCAP;

    dim3 blk(256);
    hipMemsetAsync(degc, 0, (size_t)(n + 1) * sizeof(int), stream);  // degc + ocnt
    k_ell <<<(e + 255) / 256, blk, 0, stream>>>(src, dst, degc, ocnt, oflow, ell, e, n);
    k_dinv<<<(n + 255) / 256, blk, 0, stream>>>(degc, dinv, n);
    k_agg_gemm<<<2048, blk, 0, stream>>>(x, W, bias, dinv, degc, ell, out, n);
    k_oflow<<<64, 64, 0, stream>>>(x, W, dinv, ocnt, oflow, out);
}

// Round 8
// 186.905 us; speedup vs baseline: 1.9011x; 1.0661x over previous
//
#include <hip/hip_runtime.h>

#define NF 64
#define ELLS 48
#define OCAP 65536

// ---------------- single-pass row-major ELL build ----------------
// ell[d*ELLS + slot] = src. Atomics dominate (write pattern irrelevant: R6 vs R7).
// Row-major gives agg a dense coalesced 192B read per node.

__global__ __launch_bounds__(256) void k_ell(const int* __restrict__ src,
                                             const int* __restrict__ dst,
                                             int* degc, int* ocnt, int* oflow,
                                             int* __restrict__ ell, int e) {
    int i2 = (blockIdx.x * 256 + threadIdx.x) * 2;
    if (i2 + 1 < e) {
        int2 s2 = *reinterpret_cast<const int2*>(src + i2);
        int2 d2 = *reinterpret_cast<const int2*>(dst + i2);
        int slot0 = atomicAdd(&degc[d2.x], 1);
        if (slot0 < ELLS) ell[(long)d2.x * ELLS + slot0] = s2.x;
        else { int o = atomicAdd(ocnt, 1); if (o < OCAP) { oflow[2*o] = s2.x; oflow[2*o+1] = d2.x; } }
        int slot1 = atomicAdd(&degc[d2.y], 1);
        if (slot1 < ELLS) ell[(long)d2.y * ELLS + slot1] = s2.y;
        else { int o = atomicAdd(ocnt, 1); if (o < OCAP) { oflow[2*o] = s2.y; oflow[2*o+1] = d2.y; } }
    } else if (i2 < e) {
        int s = src[i2], d = dst[i2];
        int slot = atomicAdd(&degc[d], 1);
        if (slot < ELLS) ell[(long)d * ELLS + slot] = s;
        else { int o = atomicAdd(ocnt, 1); if (o < OCAP) { oflow[2*o] = s; oflow[2*o+1] = d; } }
    }
}

__global__ __launch_bounds__(256) void k_dinv(const int* __restrict__ degc,
                                              float* __restrict__ dinv, int n) {
    int i = blockIdx.x * 256 + threadIdx.x;
    if (i < n) dinv[i] = rsqrtf((float)(degc[i] + 1));   // +1 self-loop
}

// ---------------- fused gather-aggregate + GEMM epilogue ----------------
// 1 node/wave, lane = feature. ELL row: lanes 0..47 read 192B dense/coalesced.
// Next-iteration ELL/degc prefetch; 8 independent gather chains; no in-loop
// barriers (vsh is wave-local).

__global__ __launch_bounds__(256) void k_agg_gemm(const float* __restrict__ x,
                                                  const float* __restrict__ W,
                                                  const float* __restrict__ bias,
                                                  const float* __restrict__ dinv,
                                                  const int* __restrict__ degc,
                                                  const int* __restrict__ ell,
                                                  float* __restrict__ out, int n) {
    __shared__ float wt[NF * NF];      // wt[k*64+j] = W[j][k]
    __shared__ float vsh[4][NF];
    int tid = threadIdx.x;
    for (int idx = tid; idx < NF * NF; idx += 256) {
        int k = idx >> 6, j = idx & 63;
        wt[idx] = W[j * NF + k];
    }
    int wv = tid >> 6, lane = tid & 63;
    float bj = bias[lane];
    __syncthreads();                   // wt staged (only barrier)

    int ngroups = (n + 3) >> 2, gs = gridDim.x;
    int g = blockIdx.x;
    int d = g * 4 + wv;
    int ev = 0, mc = 0;
    if (d < n) {
        if (lane < ELLS) ev = ell[(long)d * ELLS + lane];   // dense 192B row
        mc = degc[d];
    }
    while (g < ngroups) {
        int gn = g + gs, dn = gn * 4 + wv;
        int evn = 0, mcn = 0;
        if (gn < ngroups && dn < n) {          // prefetch next iteration
            if (lane < ELLS) evn = ell[(long)dn * ELLS + lane];
            mcn = degc[dn];
        }
        if (d < n) {
            float dd = rsqrtf((float)(mc + 1));
            int m = min(mc, ELLS);
            float a0 = x[(long)d * NF + lane] * dd;    // self term
            float a1 = 0.f, a2 = 0.f, a3 = 0.f, a4 = 0.f, a5 = 0.f, a6 = 0.f, a7 = 0.f;
            for (int j = 0; j < m; j += 8) {           // 8 independent gather chains
                int s0 = __shfl(ev, j + 0), s1 = __shfl(ev, j + 1);
                int s2 = __shfl(ev, j + 2), s3 = __shfl(ev, j + 3);
                int s4 = __shfl(ev, j + 4), s5 = __shfl(ev, j + 5);
                int s6 = __shfl(ev, j + 6), s7 = __shfl(ev, j + 7);
                bool b0 = j + 0 < m, b1 = j + 1 < m, b2 = j + 2 < m, b3 = j + 3 < m;
                bool b4 = j + 4 < m, b5 = j + 5 < m, b6 = j + 6 < m, b7 = j + 7 < m;
                s0 = b0 ? s0 : 0; s1 = b1 ? s1 : 0; s2 = b2 ? s2 : 0; s3 = b3 ? s3 : 0;
                s4 = b4 ? s4 : 0; s5 = b5 ? s5 : 0; s6 = b6 ? s6 : 0; s7 = b7 ? s7 : 0;
                float w0 = b0 ? dinv[s0] : 0.f, w1 = b1 ? dinv[s1] : 0.f;
                float w2 = b2 ? dinv[s2] : 0.f, w3 = b3 ? dinv[s3] : 0.f;
                float w4 = b4 ? dinv[s4] : 0.f, w5 = b5 ? dinv[s5] : 0.f;
                float w6 = b6 ? dinv[s6] : 0.f, w7 = b7 ? dinv[s7] : 0.f;
                a0 = fmaf(x[(long)s0 * NF + lane], w0, a0);
                a1 = fmaf(x[(long)s1 * NF + lane], w1, a1);
                a2 = fmaf(x[(long)s2 * NF + lane], w2, a2);
                a3 = fmaf(x[(long)s3 * NF + lane], w3, a3);
                a4 = fmaf(x[(long)s4 * NF + lane], w4, a4);
                a5 = fmaf(x[(long)s5 * NF + lane], w5, a5);
                a6 = fmaf(x[(long)s6 * NF + lane], w6, a6);
                a7 = fmaf(x[(long)s7 * NF + lane], w7, a7);
            }
            float v = dd * (((a0 + a1) + (a2 + a3)) + ((a4 + a5) + (a6 + a7)));

            vsh[wv][lane] = v;                 // wave-local exchange, no barrier
            float r = bj;
#pragma unroll
            for (int k0 = 0; k0 < NF; k0 += 4) {
                float4 bv = *reinterpret_cast<const float4*>(&vsh[wv][k0]);  // broadcast
                r = fmaf(bv.x, wt[(k0 + 0) * NF + lane], r);
                r = fmaf(bv.y, wt[(k0 + 1) * NF + lane], r);
                r = fmaf(bv.z, wt[(k0 + 2) * NF + lane], r);
                r = fmaf(bv.w, wt[(k0 + 3) * NF + lane], r);
            }
            out[(long)d * NF + lane] = r;
        }
        g = gn; d = dn; ev = evn; mc = mcn;
    }
}

// ---------------- overflow fixup (post-GEMM, by linearity) ----------------
__global__ __launch_bounds__(64) void k_oflow(const float* __restrict__ x,
                                              const float* __restrict__ W,
                                              const float* __restrict__ dinv,
                                              const int* __restrict__ ocnt,
                                              const int* __restrict__ oflow,
                                              float* out) {
    int c = *ocnt; if (c > OCAP) c = OCAP;
    int lane = threadIdx.x;
    for (int o = blockIdx.x; o < c; o += gridDim.x) {
        int s = oflow[2 * o], d = oflow[2 * o + 1];
        float norm = dinv[s] * dinv[d];
        float r = 0.f;
        for (int k = 0; k < NF; ++k)
            r = fmaf(x[(long)s * NF + k], W[lane * NF + k], r);
        atomicAdd(&out[(long)d * NF + lane], norm * r);
    }
}

// ---------------- launch ----------------

extern "C" void kernel_launch(void* const* d_in, const int* in_sizes, int n_in,
                              void* d_out, int out_size, void* d_ws, size_t ws_size,
                              hipStream_t stream) {
    const float* x    = (const float*)d_in[0];
    const int*   ei   = (const int*)d_in[1];   // harness pushes integers as int32
    const float* W    = (const float*)d_in[2];
    const float* bias = (const float*)d_in[3];
    float*       out  = (float*)d_out;

    const int n = in_sizes[0] / NF;       // 100000
    const int e = in_sizes[1] / 2;        // 1250000
    const int* src = ei;
    const int* dst = ei + e;

    // ws layout (~20.5MB): degc n | ocnt 1 | dinv n | oflow 2*OCAP | ell n*ELLS
    int*   degc  = (int*)d_ws;
    int*   ocnt  = degc + n;
    float* dinv  = (float*)(ocnt + 1);
    int*   oflow = (int*)(dinv + n);
    int*   ell   = oflow + 2 * OCAP;

    dim3 blk(256);
    hipMemsetAsync(degc, 0, (size_t)(n + 1) * sizeof(int), stream);  // degc + ocnt
    int ethreads = (e + 1) / 2;
    k_ell <<<(ethreads + 255) / 256, blk, 0, stream>>>(src, dst, degc, ocnt, oflow, ell, e);
    k_dinv<<<(n + 255) / 256, blk, 0, stream>>>(degc, dinv, n);
    k_agg_gemm<<<2048, blk, 0, stream>>>(x, W, bias, dinv, degc, ell, out, n);
    k_oflow<<<64, 64, 0, stream>>>(x, W, dinv, ocnt, oflow, out);
}

// Round 9
// 146.420 us; speedup vs baseline: 2.4268x; 1.2765x over previous
//
#include <hip/hip_runtime.h>

#define NF 64
#define ELLS 48
#define OCAP 65536

// ---------------- single-pass row-major ELL build, XCD-windowed ----------------
// Group g = blockIdx%8 (presumed XCD round-robin) handles only dst in window g.
// All writes to an ELL line then come from one XCD whose hot window (2.4MB)
// fits its 4MB L2 -> line accumulates all slot-writes, written back once.
// Correct regardless of the real blockIdx->XCD mapping (windows partition dst).

__global__ __launch_bounds__(256) void k_ell(const int* __restrict__ src,
                                             const int* __restrict__ dst,
                                             int* degc, int* ocnt, int* oflow,
                                             int* __restrict__ ell, int e, int n) {
    int grp = blockIdx.x & 7;
    int chunk = (n + 7) >> 3;
    int lo = grp * chunk;
    int hi = min(lo + chunk, n);
    int nb = gridDim.x >> 3;          // blocks per group
    int bi = blockIdx.x >> 3;         // block index within group
    for (int i = bi * 256 + threadIdx.x; i < e; i += nb * 256) {
        int d = dst[i];
        if (d < lo || d >= hi) continue;
        int s = src[i];
        int slot = atomicAdd(&degc[d], 1);
        if (slot < ELLS) {
            ell[(long)d * ELLS + slot] = s;
        } else {                                   // P(deg>48)~1e-13; correctness fallback
            int o = atomicAdd(ocnt, 1);
            if (o < OCAP) { oflow[2 * o] = s; oflow[2 * o + 1] = d; }
        }
    }
}

__global__ __launch_bounds__(256) void k_dinv(const int* __restrict__ degc,
                                              float* __restrict__ dinv, int n) {
    int i = blockIdx.x * 256 + threadIdx.x;
    if (i < n) dinv[i] = rsqrtf((float)(degc[i] + 1));   // +1 self-loop
}

// ---------------- fused gather-aggregate + GEMM epilogue ----------------
// (unchanged from R8: 1 node/wave, lane = feature, dense 192B ELL row read,
// next-iteration prefetch, 8 independent gather chains, no in-loop barriers)

__global__ __launch_bounds__(256) void k_agg_gemm(const float* __restrict__ x,
                                                  const float* __restrict__ W,
                                                  const float* __restrict__ bias,
                                                  const float* __restrict__ dinv,
                                                  const int* __restrict__ degc,
                                                  const int* __restrict__ ell,
                                                  float* __restrict__ out, int n) {
    __shared__ float wt[NF * NF];      // wt[k*64+j] = W[j][k]
    __shared__ float vsh[4][NF];
    int tid = threadIdx.x;
    for (int idx = tid; idx < NF * NF; idx += 256) {
        int k = idx >> 6, j = idx & 63;
        wt[idx] = W[j * NF + k];
    }
    int wv = tid >> 6, lane = tid & 63;
    float bj = bias[lane];
    __syncthreads();                   // wt staged (only barrier)

    int ngroups = (n + 3) >> 2, gs = gridDim.x;
    int g = blockIdx.x;
    int d = g * 4 + wv;
    int ev = 0, mc = 0;
    if (d < n) {
        if (lane < ELLS) ev = ell[(long)d * ELLS + lane];   // dense 192B row
        mc = degc[d];
    }
    while (g < ngroups) {
        int gn = g + gs, dn = gn * 4 + wv;
        int evn = 0, mcn = 0;
        if (gn < ngroups && dn < n) {          // prefetch next iteration
            if (lane < ELLS) evn = ell[(long)dn * ELLS + lane];
            mcn = degc[dn];
        }
        if (d < n) {
            float dd = rsqrtf((float)(mc + 1));
            int m = min(mc, ELLS);
            float a0 = x[(long)d * NF + lane] * dd;    // self term
            float a1 = 0.f, a2 = 0.f, a3 = 0.f, a4 = 0.f, a5 = 0.f, a6 = 0.f, a7 = 0.f;
            for (int j = 0; j < m; j += 8) {           // 8 independent gather chains
                int s0 = __shfl(ev, j + 0), s1 = __shfl(ev, j + 1);
                int s2 = __shfl(ev, j + 2), s3 = __shfl(ev, j + 3);
                int s4 = __shfl(ev, j + 4), s5 = __shfl(ev, j + 5);
                int s6 = __shfl(ev, j + 6), s7 = __shfl(ev, j + 7);
                bool b0 = j + 0 < m, b1 = j + 1 < m, b2 = j + 2 < m, b3 = j + 3 < m;
                bool b4 = j + 4 < m, b5 = j + 5 < m, b6 = j + 6 < m, b7 = j + 7 < m;
                s0 = b0 ? s0 : 0; s1 = b1 ? s1 : 0; s2 = b2 ? s2 : 0; s3 = b3 ? s3 : 0;
                s4 = b4 ? s4 : 0; s5 = b5 ? s5 : 0; s6 = b6 ? s6 : 0; s7 = b7 ? s7 : 0;
                float w0 = b0 ? dinv[s0] : 0.f, w1 = b1 ? dinv[s1] : 0.f;
                float w2 = b2 ? dinv[s2] : 0.f, w3 = b3 ? dinv[s3] : 0.f;
                float w4 = b4 ? dinv[s4] : 0.f, w5 = b5 ? dinv[s5] : 0.f;
                float w6 = b6 ? dinv[s6] : 0.f, w7 = b7 ? dinv[s7] : 0.f;
                a0 = fmaf(x[(long)s0 * NF + lane], w0, a0);
                a1 = fmaf(x[(long)s1 * NF + lane], w1, a1);
                a2 = fmaf(x[(long)s2 * NF + lane], w2, a2);
                a3 = fmaf(x[(long)s3 * NF + lane], w3, a3);
                a4 = fmaf(x[(long)s4 * NF + lane], w4, a4);
                a5 = fmaf(x[(long)s5 * NF + lane], w5, a5);
                a6 = fmaf(x[(long)s6 * NF + lane], w6, a6);
                a7 = fmaf(x[(long)s7 * NF + lane], w7, a7);
            }
            float v = dd * (((a0 + a1) + (a2 + a3)) + ((a4 + a5) + (a6 + a7)));

            vsh[wv][lane] = v;                 // wave-local exchange, no barrier
            float r = bj;
#pragma unroll
            for (int k0 = 0; k0 < NF; k0 += 4) {
                float4 bv = *reinterpret_cast<const float4*>(&vsh[wv][k0]);  // broadcast
                r = fmaf(bv.x, wt[(k0 + 0) * NF + lane], r);
                r = fmaf(bv.y, wt[(k0 + 1) * NF + lane], r);
                r = fmaf(bv.z, wt[(k0 + 2) * NF + lane], r);
                r = fmaf(bv.w, wt[(k0 + 3) * NF + lane], r);
            }
            out[(long)d * NF + lane] = r;
        }
        g = gn; d = dn; ev = evn; mc = mcn;
    }
}

// ---------------- overflow fixup (post-GEMM, by linearity) ----------------
__global__ __launch_bounds__(64) void k_oflow(const float* __restrict__ x,
                                              const float* __restrict__ W,
                                              const float* __restrict__ dinv,
                                              const int* __restrict__ ocnt,
                                              const int* __restrict__ oflow,
                                              float* out) {
    int c = *ocnt; if (c > OCAP) c = OCAP;
    int lane = threadIdx.x;
    for (int o = blockIdx.x; o < c; o += gridDim.x) {
        int s = oflow[2 * o], d = oflow[2 * o + 1];
        float norm = dinv[s] * dinv[d];
        float r = 0.f;
        for (int k = 0; k < NF; ++k)
            r = fmaf(x[(long)s * NF + k], W[lane * NF + k], r);
        atomicAdd(&out[(long)d * NF + lane], norm * r);
    }
}

// ---------------- launch ----------------

extern "C" void kernel_launch(void* const* d_in, const int* in_sizes, int n_in,
                              void* d_out, int out_size, void* d_ws, size_t ws_size,
                              hipStream_t stream) {
    const float* x    = (const float*)d_in[0];
    const int*   ei   = (const int*)d_in[1];   // harness pushes integers as int32
    const float* W    = (const float*)d_in[2];
    const float* bias = (const float*)d_in[3];
    float*       out  = (float*)d_out;

    const int n = in_sizes[0] / NF;       // 100000
    const int e = in_sizes[1] / 2;        // 1250000
    const int* src = ei;
    const int* dst = ei + e;

    // ws layout (~20.5MB): degc n | ocnt 1 | dinv n | oflow 2*OCAP | ell n*ELLS
    int*   degc  = (int*)d_ws;
    int*   ocnt  = degc + n;
    float* dinv  = (float*)(ocnt + 1);
    int*   oflow = (int*)(dinv + n);
    int*   ell   = oflow + 2 * OCAP;

    dim3 blk(256);
    hipMemsetAsync(degc, 0, (size_t)(n + 1) * sizeof(int), stream);  // degc + ocnt
    k_ell <<<2048, blk, 0, stream>>>(src, dst, degc, ocnt, oflow, ell, e, n);
    k_dinv<<<(n + 255) / 256, blk, 0, stream>>>(degc, dinv, n);
    k_agg_gemm<<<2048, blk, 0, stream>>>(x, W, bias, dinv, degc, ell, out, n);
    k_oflow<<<64, 64, 0, stream>>>(x, W, dinv, ocnt, oflow, out);
}